// Round 18
// baseline (94.757 us; speedup 1.0000x reference)
//
#include <hip/hip_runtime.h>

#define NPTS 16384
#define NBATCH 256
constexpr int THREADS = 512;             // 8 waves per block
constexpr int NCHUNK  = 4;               // chunks per row
constexpr int CHPTS   = NPTS / NCHUNK;   // 4096 points per chunk
constexpr int NBLK    = NBATCH * NCHUNK; // 1024 blocks -> 4/CU -> 32 waves/CU
constexpr int NW      = THREADS / 64;    // 8
// lane i of wave w owns windows g=0,1 at chunk*4096 + w*512 + g*256 + i*4.
// Every load: 64 lanes x 16B contiguous, nt-flagged. Cross-chunk carry via
// immediate (non-chained) per-chunk aggregate publish + <=3 flag polls.

typedef float f32x4 __attribute__((ext_vector_type(4)));

__device__ __forceinline__ f32x4 ld4nt(const float* p) {
  return __builtin_nontemporal_load(reinterpret_cast<const f32x4*>(p));
}

struct Agg { float x, y, z; unsigned int flag; };  // 16 B

struct Ws {
  unsigned int counter;      // execution-order ticket
  unsigned int pad[3];
  Agg agg[NCHUNK][NBATCH];   // per-(chunk,row) aggregates
};
constexpr size_t WS_ZERO_BYTES = sizeof(Ws);   // 16 + 16 KB

__global__ __launch_bounds__(THREADS, 4) void chunk_kernel(
    const float* __restrict__ o3, const float* __restrict__ s3,
    const float* __restrict__ o2, const float* __restrict__ s2,
    const float* __restrict__ df, Ws* __restrict__ ws,
    float* __restrict__ out) {
  const int t = threadIdx.x;
  const int lane = t & 63;
  const int wave = t >> 6;

  __shared__ unsigned int ticket_s;
  __shared__ float wtot[3][NW];
  __shared__ float carry_s[3];
  __shared__ float redbuf[NW];

  // execution-order ticket: all chunk-0 blocks precede chunk-1, etc.
  if (t == 0) ticket_s = atomicAdd(&ws->counter, 1u);
  __syncthreads();
  const int vb = (int)ticket_s;
  const int c = vb >> 8;          // chunk index (0..3)
  const int b = vb & (NBATCH - 1);// row

  const float* r3p = s3 + (size_t)b * 3 * NPTS;
  const float* t3p = r3p + NPTS;
  const float* p3p = r3p + 2 * NPTS;
  const float* r2p = s2 + (size_t)b * 3 * NPTS;
  const float* t2p = r2p + NPTS;
  const float* p2p = r2p + 2 * NPTS;
  const float* dtp = df + (size_t)b * 2 * NPTS;
  const float* dpp = dtp + NPTS;

  const int cbase = c * CHPTS + wave * 512;

  // ---- Phase 1: nt-stream, trig, per-window prefix + wave scan ----
  float px[2][4], py[2][4], pz[2][4];
  float segx[2], segy[2], segz[2];
  float runx = 0.f, runy = 0.f, runz = 0.f;
  #pragma unroll
  for (int g = 0; g < 2; ++g) {
    const int idx = cbase + g * 256 + lane * 4;
    f32x4 R3 = ld4nt(r3p + idx), T3 = ld4nt(t3p + idx);
    f32x4 P3 = ld4nt(p3p + idx), R2 = ld4nt(r2p + idx);
    f32x4 T2 = ld4nt(t2p + idx), P2 = ld4nt(p2p + idx);
    f32x4 DT = ld4nt(dtp + idx), DP = ld4nt(dpp + idx);
    float sx = 0.f, sy = 0.f, sz = 0.f;
    #pragma unroll
    for (int k = 0; k < 4; ++k) {
      float r3v = R3[k];
      float th3 = T3[k] + DT[k];
      float ph3 = P3[k] + DP[k];
      float r2v = R2[k];
      float th2 = T2[k];
      float ph2 = P2[k];
      float st3 = __sinf(th3), ct3 = __cosf(th3);
      float sp3 = __sinf(ph3), cp3 = __cosf(ph3);
      float st2 = __sinf(th2), ct2 = __cosf(th2);
      float sp2 = __sinf(ph2), cp2 = __cosf(ph2);
      sx += r3v * st3 * cp3 - r2v * st2 * cp2; px[g][k] = sx;
      sy += r3v * st3 * sp3 - r2v * st2 * sp2; py[g][k] = sy;
      sz += r3v * ct3 - r2v * ct2;             pz[g][k] = sz;
    }
    float ix = sx, iy = sy, iz = sz;
    #pragma unroll
    for (int off = 1; off < 64; off <<= 1) {
      float ax = __shfl_up(ix, off, 64);
      float ay = __shfl_up(iy, off, 64);
      float az = __shfl_up(iz, off, 64);
      if (lane >= off) { ix += ax; iy += ay; iz += az; }
    }
    segx[g] = runx + ix - sx;
    segy[g] = runy + iy - sy;
    segz[g] = runz + iz - sz;
    runx += __shfl(ix, 63, 64);
    runy += __shfl(iy, 63, 64);
    runz += __shfl(iz, 63, 64);
  }

  if (lane == 0) { wtot[0][wave] = runx; wtot[1][wave] = runy; wtot[2][wave] = runz; }
  __syncthreads();

  // wave offset within block + block total
  float wx = 0.f, wy = 0.f, wz = 0.f;
  float btx = 0.f, bty = 0.f, btz = 0.f;
  #pragma unroll
  for (int w = 0; w < NW; ++w) {
    float vx = wtot[0][w], vy = wtot[1][w], vz = wtot[2][w];
    if (w < wave) { wx += vx; wy += vy; wz += vz; }
    btx += vx; bty += vy; btz += vz;
  }

  // ---- publish own aggregate immediately; then poll <=3 predecessors ----
  if (t == 0) {
    Agg* mine = &ws->agg[c][b];
    __hip_atomic_store(&mine->x, btx, __ATOMIC_RELAXED, __HIP_MEMORY_SCOPE_AGENT);
    __hip_atomic_store(&mine->y, bty, __ATOMIC_RELAXED, __HIP_MEMORY_SCOPE_AGENT);
    __hip_atomic_store(&mine->z, btz, __ATOMIC_RELAXED, __HIP_MEMORY_SCOPE_AGENT);
    __hip_atomic_store(&mine->flag, 1u, __ATOMIC_RELEASE, __HIP_MEMORY_SCOPE_AGENT);
    float cx = 0.f, cy = 0.f, cz = 0.f;
    for (int cc = 0; cc < c; ++cc) {
      Agg* p = &ws->agg[cc][b];
      while (__hip_atomic_load(&p->flag, __ATOMIC_ACQUIRE,
                               __HIP_MEMORY_SCOPE_AGENT) == 0u) {
        __builtin_amdgcn_s_sleep(1);
      }
      cx += __hip_atomic_load(&p->x, __ATOMIC_RELAXED, __HIP_MEMORY_SCOPE_AGENT);
      cy += __hip_atomic_load(&p->y, __ATOMIC_RELAXED, __HIP_MEMORY_SCOPE_AGENT);
      cz += __hip_atomic_load(&p->z, __ATOMIC_RELAXED, __HIP_MEMORY_SCOPE_AGENT);
    }
    carry_s[0] = cx; carry_s[1] = cy; carry_s[2] = cz;
  }
  __syncthreads();

  // row carry = origin diff + preceding chunk totals
  const float ox = o3[b * 3 + 0] - o2[b * 3 + 0];
  const float oy = o3[b * 3 + 1] - o2[b * 3 + 1];
  const float oz = o3[b * 3 + 2] - o2[b * 3 + 2];
  const float Cx = ox + carry_s[0] + wx;
  const float Cy = oy + carry_s[1] + wy;
  const float Cz = oz + carry_s[2] + wz;

  // ---- Phase 2: abs over in-register prefixes ----
  float acc = 0.f;
  #pragma unroll
  for (int g = 0; g < 2; ++g) {
    const float gx = Cx + segx[g], gy = Cy + segy[g], gz = Cz + segz[g];
    #pragma unroll
    for (int k = 0; k < 4; ++k) {
      acc += fabsf(gx + px[g][k]) + fabsf(gy + py[g][k]) + fabsf(gz + pz[g][k]);
    }
  }
  if (c == 0 && t == 0) acc += fabsf(ox) + fabsf(oy) + fabsf(oz);  // j=0 term

  // ---- block reduction + one atomic per block ----
  #pragma unroll
  for (int off = 32; off > 0; off >>= 1) acc += __shfl_down(acc, off, 64);
  if (lane == 0) redbuf[wave] = acc;
  __syncthreads();
  if (t == 0) {
    float s = 0.f;
    #pragma unroll
    for (int w = 0; w < NW; ++w) s += redbuf[w];
    atomicAdd(out, s * (1.0f / (float)(NPTS + 1)));
  }
}

extern "C" void kernel_launch(void* const* d_in, const int* in_sizes, int n_in,
                              void* d_out, int out_size, void* d_ws, size_t ws_size,
                              hipStream_t stream) {
  const float* o3 = (const float*)d_in[0];  // origin_3D      (B,3,1)
  const float* s3 = (const float*)d_in[1];  // spherical_3D   (B,3,N)
  const float* o2 = (const float*)d_in[2];  // origin_2D      (B,3,1)
  const float* s2 = (const float*)d_in[3];  // spherical_2D   (B,3,N)
  const float* df = (const float*)d_in[4];  // deformation    (B,2,N)
  float* out = (float*)d_out;
  Ws* ws = (Ws*)d_ws;

  // ticket + flags must be zero each (replayed) launch; out accumulates.
  hipMemsetAsync(ws, 0, WS_ZERO_BYTES, stream);
  hipMemsetAsync(out, 0, sizeof(float) * out_size, stream);
  chunk_kernel<<<NBLK, THREADS, 0, stream>>>(o3, s3, o2, s2, df, ws, out);
}